// Round 6
// baseline (3765.157 us; speedup 1.0000x reference)
//
#include <hip/hip_runtime.h>
#include <math.h>

#define NPTS 8192
#define LGAB2 (-13.0f)   // log2(1/8192) == log(1/8192)*log2(e)
#define NWAVE 16         // waves per block (1024 threads)

typedef __attribute__((ext_vector_type(2))) float f2;

__device__ __forceinline__ float fexp2(float x){
#if __has_builtin(__builtin_amdgcn_exp2f)
  return __builtin_amdgcn_exp2f(x);
#else
  return exp2f(x);
#endif
}
__device__ __forceinline__ f2 ffma2(f2 a, f2 b, f2 c){
  return __builtin_elementwise_fma(a, b, c);   // v_pk_fma_f32
}
__device__ __forceinline__ f2 fmax2(f2 a, f2 b){
  return __builtin_elementwise_max(a, b);      // v_pk_max_f32
}

// Column pack layout: pair-transposed. For columns (2p, 2p+1) of softmin slot s,
// float4[2p]   = (x_2p, x_2p+1, y_2p, y_2p+1)
// float4[2p+1] = (z_2p, z_2p+1, w_2p, w_2p+1)   where w = h-term.

// Pack per-point data: (p0,p1,p2, |p|^2) and initial column packs (duals = 0).
__global__ __launch_bounds__(256) void ws_setup(
    const float* __restrict__ x, const float* __restrict__ y,
    float4* __restrict__ xp, float4* __restrict__ yp,
    float4* __restrict__ colpack, float inv0ce)
{
  int t = blockIdx.x * 256 + threadIdx.x;
  if (t >= NPTS) return;
  float x0 = x[3*t], x1 = x[3*t+1], x2 = x[3*t+2];
  float xs = x0*x0 + x1*x1 + x2*x2;
  float y0 = y[3*t], y1 = y[3*t+1], y2 = y[3*t+2];
  float ys = y0*y0 + y1*y1 + y2*y2;
  xp[t] = make_float4(x0,x1,x2,xs);
  yp[t] = make_float4(y0,y1,y2,ys);
  float hx = LGAB2 - 0.5f*xs*inv0ce;
  float hy = LGAB2 - 0.5f*ys*inv0ce;
  int p = t >> 1, sub = t & 1;
  {
    float* c0 = (float*)(colpack + 0*NPTS);
    c0[p*8+sub] = y0; c0[p*8+2+sub] = y1; c0[p*8+4+sub] = y2; c0[p*8+6+sub] = hy;
    float* c3 = (float*)(colpack + 3*NPTS);
    c3[p*8+sub] = y0; c3[p*8+2+sub] = y1; c3[p*8+4+sub] = y2; c3[p*8+6+sub] = hy;
  }
  {
    float* c1 = (float*)(colpack + 1*NPTS);
    c1[p*8+sub] = x0; c1[p*8+2+sub] = x1; c1[p*8+4+sub] = x2; c1[p*8+6+sub] = hx;
    float* c2 = (float*)(colpack + 2*NPTS);
    c2[p*8+sub] = x0; c2[p*8+2+sub] = x1; c2[p*8+4+sub] = x2; c2[p*8+6+sub] = hx;
  }
}

// One phase: 4 softmins (ft,gt,pt,qt). Grid 512 blocks x 1024 threads:
// s = b>>7 selects the softmin, 128 blocks x 64 rows each. lane = row,
// 16 waves split j into 16x512. Inner loop: packed fp32 VOP3P with manual
// register double-buffer prefetch (~1.5 pair-groups ahead) to hide L2 latency.
// kind: 0 = assign (init), 1 = 0.5*(P+T) average (loop), 2 = final (write Tfin)
__global__ __launch_bounds__(1024, 8) void ws_softmin(
    const float4* __restrict__ xp, const float4* __restrict__ yp,
    const float4* __restrict__ cps, float4* __restrict__ cpd,
    float* __restrict__ P, float* __restrict__ Tfin,
    float ce, float eps_ln2, float inv_next_ce, int kind)
{
  int b = blockIdx.x;
  int s = b >> 7;
  int rowbase = (b & 127) << 6;
  int tid = threadIdx.x;
  int lane = tid & 63;
  int w = __builtin_amdgcn_readfirstlane(tid >> 6);  // uniform wave id

  const float4* rp = (s == 0 || s == 2) ? xp : yp;
  float4 rv = rp[rowbase + lane];
  float a0 = rv.x * ce, a1 = rv.y * ce, a2 = rv.z * ce;
  float hx = -0.5f * rv.w * ce;                      // row-constant, added at end
  f2 A0 = {a0, a0}, A1 = {a1, a1}, A2 = {a2, a2};
  // wave slice: 256 pair-blocks (512 columns), 512 float4s
  const float4* pw = cps + (size_t)s * NPTS + (w << 9);

  // ---- pass 1: exact row max of v = h_j + x'.y_j (base-2 exponent units) ----
  f2 mA = {-3.0e38f, -3.0e38f}, mB = mA;
#define P1STEP(Pv, Qv, MACC) do {                                   \
    f2 X = {Pv.x, Pv.y}, Y = {Pv.z, Pv.w};                          \
    f2 Z = {Qv.x, Qv.y}, W = {Qv.z, Qv.w};                          \
    f2 t = ffma2(A2, Z, W);                                         \
    t = ffma2(A1, Y, t);                                            \
    t = ffma2(A0, X, t);                                            \
    MACC = fmax2(MACC, t);                                          \
  } while (0)
  {
    float4 aP = pw[0], aQ = pw[1];       // pair-block g
    float4 bP = pw[2], bQ = pw[3];       // pair-block g+1
    for (int g = 0; g < 254; g += 2) {
      const float4* q2 = pw + ((g + 2) << 1);
      float4 tP = q2[0], tQ = q2[1];
      P1STEP(aP, aQ, mA);
      float4 uP = q2[2], uQ = q2[3];
      P1STEP(bP, bQ, mB);
      aP = tP; aQ = tQ; bP = uP; bQ = uQ;
    }
    P1STEP(aP, aQ, mA);
    P1STEP(bP, bQ, mB);
  }
  f2 mAB = fmax2(mA, mB);
  float m = fmaxf(mAB.x, mAB.y);
  f2 M2 = {m, m};

  // ---- pass 2: sum of 2^(v - m) ----
  f2 sA = {0.f, 0.f}, sB = sA;
#define P2STEP(Pv, Qv, SACC) do {                                   \
    f2 X = {Pv.x, Pv.y}, Y = {Pv.z, Pv.w};                          \
    f2 Z = {Qv.x, Qv.y}, W = {Qv.z, Qv.w};                          \
    f2 u = ffma2(A2, Z, W - M2);                                    \
    u = ffma2(A1, Y, u);                                            \
    u = ffma2(A0, X, u);                                            \
    f2 e; e.x = fexp2(u.x); e.y = fexp2(u.y);                       \
    SACC += e;                                                      \
  } while (0)
  {
    float4 aP = pw[0], aQ = pw[1];
    float4 bP = pw[2], bQ = pw[3];
    for (int g = 0; g < 254; g += 2) {
      const float4* q2 = pw + ((g + 2) << 1);
      float4 tP = q2[0], tQ = q2[1];
      P2STEP(aP, aQ, sA);
      float4 uP = q2[2], uQ = q2[3];
      P2STEP(bP, bQ, sB);
      aP = tP; aQ = tQ; bP = uP; bQ = uQ;
    }
    P2STEP(aP, aQ, sA);
    P2STEP(bP, bQ, sB);
  }
  f2 sAB = sA + sB;
  float ssum = sAB.x + sAB.y;

  __shared__ float lm[NWAVE][64];
  __shared__ float lss[NWAVE][64];
  lm[w][lane] = m; lss[w][lane] = ssum;
  __syncthreads();

  if (tid < 64) {  // wave 0: its rv already holds row rowbase+lane data
    float M = lm[0][lane];
    #pragma unroll
    for (int k = 1; k < NWAVE; ++k) M = fmaxf(M, lm[k][lane]);
    float S = 0.f;
    #pragma unroll
    for (int k = 0; k < NWAVE; ++k) S += lss[k][lane] * fexp2(lm[k][lane] - M);
    float T = -eps_ln2 * (hx + M + log2f(S));
    int row = rowbase + lane;
    if (kind == 2) {
      Tfin[s * NPTS + row] = T;
    } else {
      float* Pr = P + s * NPTS;
      float Pn = (kind == 0) ? T : 0.5f * (Pr[row] + T);
      Pr[row] = Pn;
      // f feeds gt's columns, g feeds ft's; pp/qq feed themselves.
      int dst = (s == 0) ? 1 : ((s == 1) ? 0 : s);
      float hy = LGAB2 + (Pn - 0.5f * rv.w) * inv_next_ce;
      float* cd = (float*)(cpd + (size_t)dst * NPTS);
      int p = row >> 1, sub = row & 1;
      cd[p*8+sub]   = rv.x;
      cd[p*8+2+sub] = rv.y;
      cd[p*8+4+sub] = rv.z;
      cd[p*8+6+sub] = hy;
    }
  }
}

// loss = mean(f_fin - p_fin) + mean(g_fin - q_fin), fp64 accumulation
__global__ __launch_bounds__(256) void ws_reduce(
    const float* __restrict__ Tfin, float* __restrict__ out)
{
  int tid = threadIdx.x;
  double acc = 0.0;
  for (int i = tid; i < NPTS; i += 256) {
    acc += (double)Tfin[0*NPTS+i] - (double)Tfin[2*NPTS+i]
         + (double)Tfin[1*NPTS+i] - (double)Tfin[3*NPTS+i];
  }
  __shared__ double sd[256];
  sd[tid] = acc; __syncthreads();
  for (int k = 128; k > 0; k >>= 1) {
    if (tid < k) sd[tid] += sd[tid + k];
    __syncthreads();
  }
  if (tid == 0) out[0] = (float)(sd[0] / (double)NPTS);
}

extern "C" void kernel_launch(void* const* d_in, const int* in_sizes, int n_in,
                              void* d_out, int out_size, void* d_ws, size_t ws_size,
                              hipStream_t stream)
{
  const float* x = (const float*)d_in[0];
  const float* y = (const float*)d_in[1];
  float* out = (float*)d_out;

  char* wsp = (char*)d_ws;
  float4* xp  = (float4*)wsp;  wsp += (size_t)NPTS * 16;
  float4* yp  = (float4*)wsp;  wsp += (size_t)NPTS * 16;
  float4* cpA = (float4*)wsp;  wsp += (size_t)4 * NPTS * 16;
  float4* cpB = (float4*)wsp;  wsp += (size_t)4 * NPTS * 16;
  float*  P   = (float*)wsp;   wsp += (size_t)4 * NPTS * 4;
  float*  Tfin= (float*)wsp;   wsp += (size_t)4 * NPTS * 4;

  // geomloss epsilon schedule, replicated in f64 exactly as Python does it
  double epss[64]; int n = 0;
  double e = 4.0;                       // DIAMETER**P
  const double r = 0.9 * 0.9;          // SCALING**P
  const double target = 0.01 * 0.01;   // BLUR**P
  while (e > target && n < 60) { epss[n++] = e; e *= r; }   // n == 51
  int NPH = n + 2;                     // init + n loop iters + final

  const double L2E  = 1.4426950408889634;
  const double LN2d = 0.6931471805599453;

  float feps[64];
  feps[0] = (float)epss[0];                       // init uses eps_sched[0]
  for (int p = 1; p <= n; ++p) feps[p] = (float)epss[p-1];
  feps[n+1] = 1e-4f;                              // eps_final

  float inv0ce = (float)(L2E / (double)feps[0]);
  ws_setup<<<(NPTS + 255) / 256, 256, 0, stream>>>(x, y, xp, yp, cpA, inv0ce);

  for (int p = 0; p < NPH; ++p) {
    float epsf = feps[p];
    float ce = (float)(L2E / (double)epsf);
    float eps_ln2 = (float)((double)epsf * LN2d);
    float inv_next_ce = 0.f;
    if (p < NPH - 1) inv_next_ce = (float)(L2E / (double)feps[p+1]);
    int kind = (p == 0) ? 0 : ((p == NPH - 1) ? 2 : 1);
    const float4* src = (p & 1) ? cpB : cpA;
    float4*       dst = (p & 1) ? cpA : cpB;
    ws_softmin<<<512, 1024, 0, stream>>>(xp, yp, src, dst, P, Tfin,
                                         ce, eps_ln2, inv_next_ce, kind);
  }

  ws_reduce<<<1, 256, 0, stream>>>(Tfin, out);
}

// Round 7
// 3408.697 us; speedup vs baseline: 1.1046x; 1.1046x over previous
//
#include <hip/hip_runtime.h>
#include <math.h>

#define NPTS 8192
#define LGAB2 (-13.0f)   // log2(1/8192) == log(1/8192)*log2(e)
#define NWAVE 16         // waves per block (1024 threads)
#define NCHUNK 16        // chunks per wave slice (32 cols each)
#define SKIP_THR 26.0f   // drop chunks with max < m - 26 (2^-26 rel per term)

typedef __attribute__((ext_vector_type(2))) float f2;

__device__ __forceinline__ float fexp2(float x){
#if __has_builtin(__builtin_amdgcn_exp2f)
  return __builtin_amdgcn_exp2f(x);
#else
  return exp2f(x);
#endif
}
__device__ __forceinline__ f2 ffma2(f2 a, f2 b, f2 c){
  return __builtin_elementwise_fma(a, b, c);   // v_pk_fma_f32
}
__device__ __forceinline__ f2 fmax2(f2 a, f2 b){
  return __builtin_elementwise_max(a, b);      // v_pk_max_f32
}
__device__ __forceinline__ unsigned mexp10(unsigned v){
  v &= 1023u;
  v = (v | (v << 16)) & 0x030000FFu;
  v = (v | (v << 8))  & 0x0300F00Fu;
  v = (v | (v << 4))  & 0x030C30C3u;
  v = (v | (v << 2))  & 0x09249249u;
  return v;
}

// Morton-sort each point set (permutation-invariant: logsumexp + uniform
// weights + final mean). Block 0 sorts x, block 1 sorts y. Bitonic in LDS.
__global__ __launch_bounds__(1024) void ws_sort(
    const float* __restrict__ x, const float* __restrict__ y,
    unsigned* __restrict__ sidx)   // [0..NPTS): x order, [NPTS..2*NPTS): y order
{
  __shared__ unsigned long long sk[NPTS];   // 64 KB
  const float* p = (blockIdx.x == 0) ? x : y;
  int tid = threadIdx.x;
  for (int t = 0; t < 8; ++t) {
    int i = tid + (t << 10);
    float c0 = p[3*i], c1 = p[3*i+1], c2 = p[3*i+2];
    unsigned q0 = (unsigned)fminf(fmaxf(c0 * 1024.f, 0.f), 1023.f);
    unsigned q1 = (unsigned)fminf(fmaxf(c1 * 1024.f, 0.f), 1023.f);
    unsigned q2 = (unsigned)fminf(fmaxf(c2 * 1024.f, 0.f), 1023.f);
    unsigned long long mor = (unsigned long long)(mexp10(q0) | (mexp10(q1) << 1) | (mexp10(q2) << 2));
    sk[i] = (mor << 13) | (unsigned long long)i;
  }
  __syncthreads();
  for (int k = 2; k <= NPTS; k <<= 1) {
    for (int j = k >> 1; j > 0; j >>= 1) {
      for (int t = 0; t < 8; ++t) {
        int i = tid + (t << 10);
        int ixj = i ^ j;
        if (ixj > i) {
          unsigned long long a = sk[i], b = sk[ixj];
          bool up = ((i & k) == 0);
          if ((a > b) == up) { sk[i] = b; sk[ixj] = a; }
        }
      }
      __syncthreads();
    }
  }
  for (int t = 0; t < 8; ++t) {
    int i = tid + (t << 10);
    sidx[blockIdx.x * NPTS + i] = (unsigned)(sk[i] & 8191u);
  }
}

// Column pack layout: pair-transposed. For columns (2p, 2p+1) of softmin slot s,
// float4[2p]   = (x_2p, x_2p+1, y_2p, y_2p+1)
// float4[2p+1] = (z_2p, z_2p+1, w_2p, w_2p+1)   where w = h-term.
// All arrays live in the Morton-sorted domain.
__global__ __launch_bounds__(256) void ws_setup(
    const float* __restrict__ x, const float* __restrict__ y,
    const unsigned* __restrict__ sidx,
    float4* __restrict__ xp, float4* __restrict__ yp,
    float4* __restrict__ colpack, float inv0ce)
{
  int t = blockIdx.x * 256 + threadIdx.x;
  if (t >= NPTS) return;
  int ox = sidx[t], oy = sidx[NPTS + t];
  float x0 = x[3*ox], x1 = x[3*ox+1], x2 = x[3*ox+2];
  float xs = x0*x0 + x1*x1 + x2*x2;
  float y0 = y[3*oy], y1 = y[3*oy+1], y2 = y[3*oy+2];
  float ys = y0*y0 + y1*y1 + y2*y2;
  xp[t] = make_float4(x0,x1,x2,xs);
  yp[t] = make_float4(y0,y1,y2,ys);
  float hx = LGAB2 - 0.5f*xs*inv0ce;
  float hy = LGAB2 - 0.5f*ys*inv0ce;
  int p = t >> 1, sub = t & 1;
  {
    float* c0 = (float*)(colpack + 0*NPTS);
    c0[p*8+sub] = y0; c0[p*8+2+sub] = y1; c0[p*8+4+sub] = y2; c0[p*8+6+sub] = hy;
    float* c3 = (float*)(colpack + 3*NPTS);
    c3[p*8+sub] = y0; c3[p*8+2+sub] = y1; c3[p*8+4+sub] = y2; c3[p*8+6+sub] = hy;
  }
  {
    float* c1 = (float*)(colpack + 1*NPTS);
    c1[p*8+sub] = x0; c1[p*8+2+sub] = x1; c1[p*8+4+sub] = x2; c1[p*8+6+sub] = hx;
    float* c2 = (float*)(colpack + 2*NPTS);
    c2[p*8+sub] = x0; c2[p*8+2+sub] = x1; c2[p*8+4+sub] = x2; c2[p*8+6+sub] = hx;
  }
}

// One phase: 4 softmins (ft,gt,pt,qt). Grid 512 blocks x 1024 threads:
// s = b>>7 selects the softmin, 128 blocks x 64 (sorted-adjacent) rows each.
// lane = row, 16 waves split j into 16x512. Pass 1: chunked (16x32 cols) exact
// max, recording per-chunk maxes. Pass 2: wave-uniform chunk skip for chunks
// with max < m - 26 across all 64 lanes (safe: <= 512*2^-26 relative on S).
// kind: 0 = assign (init), 1 = 0.5*(P+T) average (loop), 2 = final (write Tfin)
__global__ __launch_bounds__(1024, 8) void ws_softmin(
    const float4* __restrict__ xp, const float4* __restrict__ yp,
    const float4* __restrict__ cps, float4* __restrict__ cpd,
    float* __restrict__ P, float* __restrict__ Tfin,
    float ce, float eps_ln2, float inv_next_ce, int kind)
{
  int b = blockIdx.x;
  int s = b >> 7;
  int rowbase = (b & 127) << 6;
  int tid = threadIdx.x;
  int lane = tid & 63;
  int w = __builtin_amdgcn_readfirstlane(tid >> 6);  // uniform wave id

  const float4* rp = (s == 0 || s == 2) ? xp : yp;
  float4 rv = rp[rowbase + lane];
  float a0 = rv.x * ce, a1 = rv.y * ce, a2 = rv.z * ce;
  float hx = -0.5f * rv.w * ce;                      // row-constant, added at end
  f2 A0 = {a0, a0}, A1 = {a1, a1}, A2 = {a2, a2};
  // wave slice: 512 columns = 16 chunks x 16 pair-blocks, 512 float4s
  const float4* pw = cps + (size_t)s * NPTS + (w << 9);

  // ---- pass 1: exact row max, per-chunk maxes ----
  float cmax[NCHUNK];
  #pragma unroll
  for (int c = 0; c < NCHUNK; ++c) {
    f2 cm = {-3.0e38f, -3.0e38f};
    #pragma unroll 4
    for (int pb = 0; pb < 16; ++pb) {
      const float4* q = pw + (((c << 4) + pb) << 1);
      float4 Pv = q[0], Qv = q[1];
      f2 X = {Pv.x, Pv.y}, Y = {Pv.z, Pv.w};
      f2 Z = {Qv.x, Qv.y}, W = {Qv.z, Qv.w};
      f2 t = ffma2(A2, Z, W);
      t = ffma2(A1, Y, t);
      t = ffma2(A0, X, t);
      cm = fmax2(cm, t);
    }
    cmax[c] = fmaxf(cm.x, cm.y);
  }
  float m = cmax[0];
  #pragma unroll
  for (int c = 1; c < NCHUNK; ++c) m = fmaxf(m, cmax[c]);

  // ---- wave-uniform chunk skip mask ----
  float thr = m - SKIP_THR;
  unsigned mask = 0;
  #pragma unroll
  for (int c = 0; c < NCHUNK; ++c)
    if (__ballot(cmax[c] > thr) != 0ull) mask |= (1u << c);
  mask = __builtin_amdgcn_readfirstlane(mask);

  // ---- pass 2: sum of 2^(v - m) over surviving chunks ----
  f2 sA = {0.f, 0.f}, sB = {0.f, 0.f};
  f2 M2 = {m, m};
  for (int c = 0; c < NCHUNK; ++c) {
    if (!((mask >> c) & 1u)) continue;
    #pragma unroll 4
    for (int pb = 0; pb < 16; ++pb) {
      const float4* q = pw + (((c << 4) + pb) << 1);
      float4 Pv = q[0], Qv = q[1];
      f2 X = {Pv.x, Pv.y}, Y = {Pv.z, Pv.w};
      f2 Z = {Qv.x, Qv.y}, W = {Qv.z, Qv.w};
      f2 u = ffma2(A2, Z, W - M2);
      u = ffma2(A1, Y, u);
      u = ffma2(A0, X, u);
      f2 e; e.x = fexp2(u.x); e.y = fexp2(u.y);
      if (pb & 1) sB += e; else sA += e;
    }
  }
  f2 sAB = sA + sB;
  float ssum = sAB.x + sAB.y;

  __shared__ float lm[NWAVE][64];
  __shared__ float lss[NWAVE][64];
  lm[w][lane] = m; lss[w][lane] = ssum;
  __syncthreads();

  if (tid < 64) {  // wave 0: its rv already holds row rowbase+lane data
    float M = lm[0][lane];
    #pragma unroll
    for (int k = 1; k < NWAVE; ++k) M = fmaxf(M, lm[k][lane]);
    float S = 0.f;
    #pragma unroll
    for (int k = 0; k < NWAVE; ++k) S += lss[k][lane] * fexp2(lm[k][lane] - M);
    float T = -eps_ln2 * (hx + M + log2f(S));
    int row = rowbase + lane;
    if (kind == 2) {
      Tfin[s * NPTS + row] = T;
    } else {
      float* Pr = P + s * NPTS;
      float Pn = (kind == 0) ? T : 0.5f * (Pr[row] + T);
      Pr[row] = Pn;
      // f feeds gt's columns, g feeds ft's; pp/qq feed themselves.
      int dst = (s == 0) ? 1 : ((s == 1) ? 0 : s);
      float hy = LGAB2 + (Pn - 0.5f * rv.w) * inv_next_ce;
      float* cd = (float*)(cpd + (size_t)dst * NPTS);
      int p = row >> 1, sub = row & 1;
      cd[p*8+sub]   = rv.x;
      cd[p*8+2+sub] = rv.y;
      cd[p*8+4+sub] = rv.z;
      cd[p*8+6+sub] = hy;
    }
  }
}

// loss = mean(f_fin - p_fin) + mean(g_fin - q_fin), fp64 accumulation
__global__ __launch_bounds__(256) void ws_reduce(
    const float* __restrict__ Tfin, float* __restrict__ out)
{
  int tid = threadIdx.x;
  double acc = 0.0;
  for (int i = tid; i < NPTS; i += 256) {
    acc += (double)Tfin[0*NPTS+i] - (double)Tfin[2*NPTS+i]
         + (double)Tfin[1*NPTS+i] - (double)Tfin[3*NPTS+i];
  }
  __shared__ double sd[256];
  sd[tid] = acc; __syncthreads();
  for (int k = 128; k > 0; k >>= 1) {
    if (tid < k) sd[tid] += sd[tid + k];
    __syncthreads();
  }
  if (tid == 0) out[0] = (float)(sd[0] / (double)NPTS);
}

extern "C" void kernel_launch(void* const* d_in, const int* in_sizes, int n_in,
                              void* d_out, int out_size, void* d_ws, size_t ws_size,
                              hipStream_t stream)
{
  const float* x = (const float*)d_in[0];
  const float* y = (const float*)d_in[1];
  float* out = (float*)d_out;

  char* wsp = (char*)d_ws;
  float4*   xp   = (float4*)wsp;   wsp += (size_t)NPTS * 16;
  float4*   yp   = (float4*)wsp;   wsp += (size_t)NPTS * 16;
  float4*   cpA  = (float4*)wsp;   wsp += (size_t)4 * NPTS * 16;
  float4*   cpB  = (float4*)wsp;   wsp += (size_t)4 * NPTS * 16;
  float*    P    = (float*)wsp;    wsp += (size_t)4 * NPTS * 4;
  float*    Tfin = (float*)wsp;    wsp += (size_t)4 * NPTS * 4;
  unsigned* sidx = (unsigned*)wsp; wsp += (size_t)2 * NPTS * 4;

  // geomloss epsilon schedule, replicated in f64 exactly as Python does it
  double epss[64]; int n = 0;
  double e = 4.0;                       // DIAMETER**P
  const double r = 0.9 * 0.9;          // SCALING**P
  const double target = 0.01 * 0.01;   // BLUR**P
  while (e > target && n < 60) { epss[n++] = e; e *= r; }   // n == 51
  int NPH = n + 2;                     // init + n loop iters + final

  const double L2E  = 1.4426950408889634;
  const double LN2d = 0.6931471805599453;

  float feps[64];
  feps[0] = (float)epss[0];                       // init uses eps_sched[0]
  for (int p = 1; p <= n; ++p) feps[p] = (float)epss[p-1];
  feps[n+1] = 1e-4f;                              // eps_final

  float inv0ce = (float)(L2E / (double)feps[0]);
  ws_sort<<<2, 1024, 0, stream>>>(x, y, sidx);
  ws_setup<<<(NPTS + 255) / 256, 256, 0, stream>>>(x, y, sidx, xp, yp, cpA, inv0ce);

  for (int p = 0; p < NPH; ++p) {
    float epsf = feps[p];
    float ce = (float)(L2E / (double)epsf);
    float eps_ln2 = (float)((double)epsf * LN2d);
    float inv_next_ce = 0.f;
    if (p < NPH - 1) inv_next_ce = (float)(L2E / (double)feps[p+1]);
    int kind = (p == 0) ? 0 : ((p == NPH - 1) ? 2 : 1);
    const float4* src = (p & 1) ? cpB : cpA;
    float4*       dst = (p & 1) ? cpA : cpB;
    ws_softmin<<<512, 1024, 0, stream>>>(xp, yp, src, dst, P, Tfin,
                                         ce, eps_ln2, inv_next_ce, kind);
  }

  ws_reduce<<<1, 256, 0, stream>>>(Tfin, out);
}

// Round 8
// 2724.723 us; speedup vs baseline: 1.3818x; 1.2510x over previous
//
#include <hip/hip_runtime.h>
#include <math.h>

#define NPTS 8192
#define LGAB2 (-13.0f)   // log2(1/8192)
#define NWAVE 16         // waves per block (1024 threads)
#define MARGIN 60.0f     // chunk skip margin vs M_est (exponent units, base 2)

typedef __attribute__((ext_vector_type(2))) float f2;

__device__ __forceinline__ float fexp2(float x){
#if __has_builtin(__builtin_amdgcn_exp2f)
  return __builtin_amdgcn_exp2f(x);
#else
  return exp2f(x);
#endif
}
__device__ __forceinline__ f2 ffma2(f2 a, f2 b, f2 c){
  return __builtin_elementwise_fma(a, b, c);   // v_pk_fma_f32
}
__device__ __forceinline__ f2 fmax2(f2 a, f2 b){
  return __builtin_elementwise_max(a, b);      // v_pk_max_f32
}
__device__ __forceinline__ f2 fmin2(f2 a, f2 b){
  return __builtin_elementwise_min(a, b);      // v_pk_min_f32
}

// ---------------- counting sort by 12-bit Morton key (16^3 cells) ------------
__global__ __launch_bounds__(1024) void ws_sort(
    const float* __restrict__ x, const float* __restrict__ y,
    unsigned* __restrict__ sidx)
{
  __shared__ unsigned hist[4096];
  __shared__ unsigned wtot[16];
  const float* p = blockIdx.x ? y : x;
  int tid = threadIdx.x;
  for (int i = tid; i < 4096; i += 1024) hist[i] = 0;
  __syncthreads();
  unsigned key[8];
  for (int t = 0; t < 8; ++t) {
    int i = tid + (t << 10);
    unsigned q0 = (unsigned)fminf(fmaxf(p[3*i  ] * 16.f, 0.f), 15.f);
    unsigned q1 = (unsigned)fminf(fmaxf(p[3*i+1] * 16.f, 0.f), 15.f);
    unsigned q2 = (unsigned)fminf(fmaxf(p[3*i+2] * 16.f, 0.f), 15.f);
    unsigned k = 0;
    #pragma unroll
    for (int bb = 0; bb < 4; ++bb)
      k |= (((q0 >> bb) & 1u) << (3*bb)) | (((q1 >> bb) & 1u) << (3*bb+1))
         | (((q2 >> bb) & 1u) << (3*bb+2));
    key[t] = k;
    atomicAdd(&hist[k], 1u);
  }
  __syncthreads();
  unsigned c0 = hist[4*tid], c1 = hist[4*tid+1], c2 = hist[4*tid+2], c3 = hist[4*tid+3];
  unsigned tsum = c0 + c1 + c2 + c3;
  int lane = tid & 63, wv = tid >> 6;
  unsigned inc = tsum;
  for (int d = 1; d < 64; d <<= 1) {
    unsigned o = __shfl_up(inc, d);
    if (lane >= d) inc += o;
  }
  if (lane == 63) wtot[wv] = inc;
  __syncthreads();
  unsigned woff = 0;
  for (int k = 0; k < wv; ++k) woff += wtot[k];
  unsigned base = woff + inc - tsum;
  hist[4*tid] = base; hist[4*tid+1] = base + c0;
  hist[4*tid+2] = base + c0 + c1; hist[4*tid+3] = base + c0 + c1 + c2;
  __syncthreads();
  for (int t = 0; t < 8; ++t) {
    int i = tid + (t << 10);
    unsigned pos = atomicAdd(&hist[key[t]], 1u);
    sidx[blockIdx.x * NPTS + pos] = i;
  }
}

// Column pack layout (sorted domain): per 2 columns, float4 (x0,x1,y0,y1) then
// float4 (z0,z1,w0,w1) where w = h-term (exponent units base 2).
__global__ __launch_bounds__(256) void ws_setup(
    const float* __restrict__ x, const float* __restrict__ y,
    const unsigned* __restrict__ sidx,
    float4* __restrict__ xp, float4* __restrict__ yp,
    float4* __restrict__ colpack, float inv0ce)
{
  int t = blockIdx.x * 256 + threadIdx.x;
  if (t >= NPTS) return;
  int ox = sidx[t], oy = sidx[NPTS + t];
  float x0 = x[3*ox], x1 = x[3*ox+1], x2 = x[3*ox+2];
  float xs = x0*x0 + x1*x1 + x2*x2;
  float y0 = y[3*oy], y1 = y[3*oy+1], y2 = y[3*oy+2];
  float ys = y0*y0 + y1*y1 + y2*y2;
  xp[t] = make_float4(x0,x1,x2,xs);
  yp[t] = make_float4(y0,y1,y2,ys);
  float hx = LGAB2 - 0.5f*xs*inv0ce;
  float hy = LGAB2 - 0.5f*ys*inv0ce;
  int p = t >> 1, sub = t & 1;
  {
    float* c0 = (float*)(colpack + 0*NPTS);
    c0[p*8+sub] = y0; c0[p*8+2+sub] = y1; c0[p*8+4+sub] = y2; c0[p*8+6+sub] = hy;
    float* c3 = (float*)(colpack + 3*NPTS);
    c3[p*8+sub] = y0; c3[p*8+2+sub] = y1; c3[p*8+4+sub] = y2; c3[p*8+6+sub] = hy;
  }
  {
    float* c1 = (float*)(colpack + 1*NPTS);
    c1[p*8+sub] = x0; c1[p*8+2+sub] = x1; c1[p*8+4+sub] = x2; c1[p*8+6+sub] = hx;
    float* c2 = (float*)(colpack + 2*NPTS);
    c2[p*8+sub] = x0; c2[p*8+2+sub] = x1; c2[p*8+4+sub] = x2; c2[p*8+6+sub] = hx;
  }
}

// 32-point chunk bounding boxes: bbox[(set*256+c)*2 + {0,1}] = lo/hi
__global__ __launch_bounds__(256) void ws_bbox(
    const float4* __restrict__ xp, const float4* __restrict__ yp,
    float4* __restrict__ bbox)
{
  int c = threadIdx.x;
  int set = blockIdx.x;
  const float4* pp = set ? yp : xp;
  float lx = 1e30f, ly = 1e30f, lz = 1e30f;
  float hxx = -1e30f, hyy = -1e30f, hzz = -1e30f;
  for (int k = 0; k < 32; ++k) {
    float4 v = pp[c*32+k];
    lx = fminf(lx, v.x); ly = fminf(ly, v.y); lz = fminf(lz, v.z);
    hxx = fmaxf(hxx, v.x); hyy = fmaxf(hyy, v.y); hzz = fmaxf(hzz, v.z);
  }
  bbox[(set*256+c)*2+0] = make_float4(lx, ly, lz, 0.f);
  bbox[(set*256+c)*2+1] = make_float4(hxx, hyy, hzz, 0.f);
}

// dmin^2 between row-block rb (64 rows = 2 chunks of row-set) and col chunk c.
// blockIdx.x = s*128+rb, threadIdx.x = c. dmin[(blockIdx.x<<8)+c].
__global__ __launch_bounds__(256) void ws_dmin(
    const float4* __restrict__ bbox, float* __restrict__ dmin)
{
  int b = blockIdx.x;
  int s = b >> 7, rb = b & 127;
  int c = threadIdx.x;
  int rset = (s == 0 || s == 2) ? 0 : 1;
  int cset = (s == 0 || s == 3) ? 1 : 0;
  float4 l0 = bbox[(rset*256 + 2*rb)*2],     h0 = bbox[(rset*256 + 2*rb)*2+1];
  float4 l1 = bbox[(rset*256 + 2*rb+1)*2],   h1 = bbox[(rset*256 + 2*rb+1)*2+1];
  float alx = fminf(l0.x, l1.x), aly = fminf(l0.y, l1.y), alz = fminf(l0.z, l1.z);
  float ahx = fmaxf(h0.x, h1.x), ahy = fmaxf(h0.y, h1.y), ahz = fmaxf(h0.z, h1.z);
  float4 bl = bbox[(cset*256 + c)*2], bh = bbox[(cset*256 + c)*2+1];
  float dx = fmaxf(0.f, fmaxf(alx - bh.x, bl.x - ahx));
  float dy = fmaxf(0.f, fmaxf(aly - bh.y, bl.y - ahy));
  float dz = fmaxf(0.f, fmaxf(alz - bh.z, bl.z - ahz));
  dmin[((size_t)b << 8) + c] = dx*dx + dy*dy + dz*dz;
}

// One phase. mode 0 (p==0): exact two-pass, full scan (seeds Mw).
// mode 1 (p>=1): single pass with M_est from previous phase's LSE (rescaled by
// rho = ce_cur/ce_prev) + geometric chunk skip (margin 60, provably <2^-40 rel).
// L = M_est + log2(sum 2^(w - M_est)) is exact for any M_est within fp32 range
// (clamp +100 vs overflow, floor 1e-30 vs total underflow).
// kind: 0 = assign (init), 1 = 0.5*(P+T) average, 2 = final (write Tfin)
__global__ __launch_bounds__(1024, 8) void ws_softmin(
    const float4* __restrict__ xp, const float4* __restrict__ yp,
    const float4* __restrict__ cps, float4* __restrict__ cpd,
    const float* __restrict__ dmin, const float* __restrict__ hmS,
    float* __restrict__ hmD, float* __restrict__ Mw,
    float* __restrict__ P, float* __restrict__ Tfin,
    float ce, float eps_ln2, float inv_next_ce, float rho, int kind, int mode)
{
  int b = blockIdx.x;
  int s = b >> 7;
  int rb = b & 127;
  int rowbase = rb << 6;
  int tid = threadIdx.x;
  int lane = tid & 63;
  int w = __builtin_amdgcn_readfirstlane(tid >> 6);

  const float4* rp = (s == 0 || s == 2) ? xp : yp;
  float4 rv = rp[rowbase + lane];
  float a0 = rv.x * ce, a1 = rv.y * ce, a2 = rv.z * ce;
  float hx = -0.5f * rv.w * ce;
  f2 A0 = {a0,a0}, A1 = {a1,a1}, A2 = {a2,a2};
  const float4* pw = cps + (size_t)s * NPTS + (w << 9);
  int row = rowbase + lane;

  __shared__ float lm[NWAVE][64];
  __shared__ float lss[NWAVE][64];
  float myMest = 0.f;

  if (mode == 0) {
    // ---- exact two-pass full scan ----
    f2 mA = {-3.0e38f, -3.0e38f}, mB = mA;
    #pragma unroll 2
    for (int pb = 0; pb < 256; pb += 2) {
      float4 P0 = pw[2*pb+0], Q0 = pw[2*pb+1];
      float4 P1 = pw[2*pb+2], Q1 = pw[2*pb+3];
      f2 X0={P0.x,P0.y}, Y0={P0.z,P0.w}, Z0={Q0.x,Q0.y}, W0={Q0.z,Q0.w};
      f2 X1={P1.x,P1.y}, Y1={P1.z,P1.w}, Z1={Q1.x,Q1.y}, W1={Q1.z,Q1.w};
      f2 t0 = ffma2(A2, Z0, W0); t0 = ffma2(A1, Y0, t0); t0 = ffma2(A0, X0, t0);
      f2 t1 = ffma2(A2, Z1, W1); t1 = ffma2(A1, Y1, t1); t1 = ffma2(A0, X1, t1);
      mA = fmax2(mA, t0); mB = fmax2(mB, t1);
    }
    f2 mAB = fmax2(mA, mB);
    float m = fmaxf(mAB.x, mAB.y);
    f2 M2 = {m, m};
    f2 sA = {0.f,0.f}, sB = {0.f,0.f};
    #pragma unroll 2
    for (int pb = 0; pb < 256; pb += 2) {
      float4 P0 = pw[2*pb+0], Q0 = pw[2*pb+1];
      float4 P1 = pw[2*pb+2], Q1 = pw[2*pb+3];
      f2 X0={P0.x,P0.y}, Y0={P0.z,P0.w}, Z0={Q0.x,Q0.y}, W0={Q0.z,Q0.w};
      f2 X1={P1.x,P1.y}, Y1={P1.z,P1.w}, Z1={Q1.x,Q1.y}, W1={Q1.z,Q1.w};
      f2 u0 = ffma2(A2, Z0, W0 - M2); u0 = ffma2(A1, Y0, u0); u0 = ffma2(A0, X0, u0);
      f2 u1 = ffma2(A2, Z1, W1 - M2); u1 = ffma2(A1, Y1, u1); u1 = ffma2(A0, X1, u1);
      f2 e0, e1;
      e0.x = fexp2(u0.x); e0.y = fexp2(u0.y);
      e1.x = fexp2(u1.x); e1.y = fexp2(u1.y);
      sA += e0; sB += e1;
    }
    f2 sAB = sA + sB;
    lm[w][lane] = m;
    lss[w][lane] = sAB.x + sAB.y;
  } else {
    // ---- single pass with M_est + geometric chunk skip ----
    float Mest = fmaf(Mw[s * NPTS + row] - LGAB2, rho, LGAB2);
    myMest = Mest;
    float thr = Mest - MARGIN;
    unsigned mask = 0u;
    #pragma unroll
    for (int c = 0; c < 16; ++c) {
      int gc = (w << 4) + c;
      float Wc = hmS[s*256 + gc] - 0.5f * ce * dmin[((size_t)b << 8) + gc];
      if (__ballot(Wc > thr)) mask |= (1u << c);
    }
    if (mask == 0u) mask = 0xFFFFu;     // safety: never drop everything
    mask = __builtin_amdgcn_readfirstlane(mask);
    float Mv = Mest - hx;
    f2 M2 = {Mv, Mv};
    f2 C100 = {100.f, 100.f};
    f2 sA = {0.f,0.f}, sB = {0.f,0.f};
    #pragma unroll
    for (int c = 0; c < 16; ++c) {
      if (!((mask >> c) & 1u)) continue;
      const float4* pc = pw + (c << 5);
      #pragma unroll 4
      for (int pb = 0; pb < 16; ++pb) {
        float4 Pv = pc[2*pb], Qv = pc[2*pb+1];
        f2 X={Pv.x,Pv.y}, Y={Pv.z,Pv.w}, Z={Qv.x,Qv.y}, W={Qv.z,Qv.w};
        f2 u = ffma2(A2, Z, W - M2);
        u = ffma2(A1, Y, u);
        u = ffma2(A0, X, u);
        u = fmin2(u, C100);
        f2 e; e.x = fexp2(u.x); e.y = fexp2(u.y);
        if (pb & 1) sB += e; else sA += e;
      }
    }
    f2 sAB = sA + sB;
    lss[w][lane] = sAB.x + sAB.y;
  }
  __syncthreads();

  if (tid < 64) {
    float L;
    if (mode == 0) {
      float M = lm[0][lane];
      #pragma unroll
      for (int k = 1; k < NWAVE; ++k) M = fmaxf(M, lm[k][lane]);
      float S = 0.f;
      #pragma unroll
      for (int k = 0; k < NWAVE; ++k) S += lss[k][lane] * fexp2(lm[k][lane] - M);
      L = hx + M + log2f(S);
    } else {
      float S = 0.f;
      #pragma unroll
      for (int k = 0; k < NWAVE; ++k) S += lss[k][lane];
      S = fmaxf(S, 1e-30f);
      L = myMest + log2f(S);
    }
    float T = -eps_ln2 * L;
    Mw[s * NPTS + row] = L;
    if (kind == 2) {
      Tfin[s * NPTS + row] = T;
    } else {
      float* Pr = P + s * NPTS;
      float Pn = (kind == 0) ? T : 0.5f * (Pr[row] + T);
      Pr[row] = Pn;
      int dst = (s == 0) ? 1 : ((s == 1) ? 0 : s);
      float hy = LGAB2 + (Pn - 0.5f * rv.w) * inv_next_ce;
      float* cd = (float*)(cpd + (size_t)dst * NPTS);
      int p = row >> 1, sub = row & 1;
      cd[p*8+sub]   = rv.x;
      cd[p*8+2+sub] = rv.y;
      cd[p*8+4+sub] = rv.z;
      cd[p*8+6+sub] = hy;
      // per-chunk hhat-max for next phase: hhat = LGAB2 + Pn*ce_next
      float hN = fmaf(Pn, inv_next_ce, LGAB2);
      #pragma unroll
      for (int d = 16; d >= 1; d >>= 1) hN = fmaxf(hN, __shfl_xor(hN, d));
      if ((lane & 31) == 0) hmD[dst*256 + 2*rb + (lane >> 5)] = hN;
    }
  }
}

// loss = mean(f_fin - p_fin) + mean(g_fin - q_fin), fp64 accumulation
__global__ __launch_bounds__(256) void ws_reduce(
    const float* __restrict__ Tfin, float* __restrict__ out)
{
  int tid = threadIdx.x;
  double acc = 0.0;
  for (int i = tid; i < NPTS; i += 256) {
    acc += (double)Tfin[0*NPTS+i] - (double)Tfin[2*NPTS+i]
         + (double)Tfin[1*NPTS+i] - (double)Tfin[3*NPTS+i];
  }
  __shared__ double sd[256];
  sd[tid] = acc; __syncthreads();
  for (int k = 128; k > 0; k >>= 1) {
    if (tid < k) sd[tid] += sd[tid + k];
    __syncthreads();
  }
  if (tid == 0) out[0] = (float)(sd[0] / (double)NPTS);
}

extern "C" void kernel_launch(void* const* d_in, const int* in_sizes, int n_in,
                              void* d_out, int out_size, void* d_ws, size_t ws_size,
                              hipStream_t stream)
{
  const float* x = (const float*)d_in[0];
  const float* y = (const float*)d_in[1];
  float* out = (float*)d_out;

  char* wsp = (char*)d_ws;
  float4*   xp   = (float4*)wsp;   wsp += (size_t)NPTS * 16;
  float4*   yp   = (float4*)wsp;   wsp += (size_t)NPTS * 16;
  float4*   cpA  = (float4*)wsp;   wsp += (size_t)4 * NPTS * 16;
  float4*   cpB  = (float4*)wsp;   wsp += (size_t)4 * NPTS * 16;
  float*    P    = (float*)wsp;    wsp += (size_t)4 * NPTS * 4;
  float*    Tfin = (float*)wsp;    wsp += (size_t)4 * NPTS * 4;
  unsigned* sidx = (unsigned*)wsp; wsp += (size_t)2 * NPTS * 4;
  float*    Mw   = (float*)wsp;    wsp += (size_t)4 * NPTS * 4;
  float*    hmA  = (float*)wsp;    wsp += (size_t)4 * 256 * 4;
  float*    hmB  = (float*)wsp;    wsp += (size_t)4 * 256 * 4;
  float4*   bbox = (float4*)wsp;   wsp += (size_t)2 * 256 * 2 * 16;
  float*    dmin = (float*)wsp;    wsp += (size_t)4 * 128 * 256 * 4;

  // geomloss epsilon schedule, replicated in f64 exactly as Python does it
  double epss[64]; int n = 0;
  double e = 4.0;                       // DIAMETER**P
  const double r = 0.9 * 0.9;          // SCALING**P
  const double target = 0.01 * 0.01;   // BLUR**P
  while (e > target && n < 60) { epss[n++] = e; e *= r; }   // n == 51
  int NPH = n + 2;                     // init + n loop iters + final

  const double L2E  = 1.4426950408889634;
  const double LN2d = 0.6931471805599453;

  float feps[64];
  feps[0] = (float)epss[0];                       // init uses eps_sched[0]
  for (int p = 1; p <= n; ++p) feps[p] = (float)epss[p-1];
  feps[n+1] = 1e-4f;                              // eps_final

  float inv0ce = (float)(L2E / (double)feps[0]);
  ws_sort<<<2, 1024, 0, stream>>>(x, y, sidx);
  ws_setup<<<(NPTS + 255) / 256, 256, 0, stream>>>(x, y, sidx, xp, yp, cpA, inv0ce);
  ws_bbox<<<2, 256, 0, stream>>>(xp, yp, bbox);
  ws_dmin<<<512, 256, 0, stream>>>(bbox, dmin);

  for (int p = 0; p < NPH; ++p) {
    float epsf = feps[p];
    float ce = (float)(L2E / (double)epsf);
    float eps_ln2 = (float)((double)epsf * LN2d);
    float inv_next_ce = 0.f;
    if (p < NPH - 1) inv_next_ce = (float)(L2E / (double)feps[p+1]);
    float rho = 1.f;
    if (p >= 1) rho = (float)((double)feps[p-1] / (double)feps[p]);
    int kind = (p == 0) ? 0 : ((p == NPH - 1) ? 2 : 1);
    int mode = (p == 0) ? 0 : 1;
    const float4* src = (p & 1) ? cpB : cpA;
    float4*       dst = (p & 1) ? cpA : cpB;
    const float*  hmS = (p & 1) ? hmB : hmA;
    float*        hmD = (p & 1) ? hmA : hmB;
    ws_softmin<<<512, 1024, 0, stream>>>(xp, yp, src, dst, dmin, hmS, hmD,
                                         Mw, P, Tfin,
                                         ce, eps_ln2, inv_next_ce, rho, kind, mode);
  }

  ws_reduce<<<1, 256, 0, stream>>>(Tfin, out);
}